// Round 14
// baseline (365.594 us; speedup 1.0000x reference)
//
#include <hip/hip_runtime.h>
#include <hip/hip_bf16.h>

// CoreAttention (ChatGLM GQA fallback) — swapped-operand 32x32x16 bf16 MFMA
// flash attention. Round 14: SPLIT-D WAVE PAIRS. r13 was stuck at 2 waves/SIMD
// because total regs = 84 VGPR + 64 acc AGPR = 148 > 128 (unified file!).
// Block = 8 waves = 4 heads x 2 d-halves; each wave: full QK^T (duplicated in
// the pair) + softmax + PV for 64 of 128 d -> o[2] = 32 AGPR, total ~112 regs
// => 4 waves/SIMD, 2 independent blocks/CU interleaving barrier phases.
// K/V/mask staged once per block via global_load_lds from pre-swizzled images.
// B=2, H=32, G=2, Q=KV=2048, D=128, fp32 in/out.

constexpr int Bn = 2, Hn = 32, Gn = 2, Qn = 2048, KVn = 2048, Dn = 128;
constexpr int WAVES = 8, QBLK = 32, HB = 4;           // 4 heads/block
constexpr int KVB = 32, NT = KVn / KVB;               // 64 kv tiles
constexpr int NT32 = KVn / 32;
constexpr float SCALE = 0.08838834764831843f;         // 1/sqrt(128)
constexpr float L2E = 1.4426950408889634f;
constexpr float SCALE2 = SCALE * L2E;

// ws: K images (2 MiB) then V images (2 MiB); needs ws >= 4 MiB.
constexpr size_t WSK_BYTES = (size_t)Bn * Gn * KVn * 256;   // 2 MiB

typedef __attribute__((ext_vector_type(16))) float f32x16;
typedef __attribute__((ext_vector_type(8))) __bf16 bf16x8;

__device__ __forceinline__ unsigned pk2(float a, float b) {
  union { __bf16 h[2]; unsigned u; } x;
  x.h[0] = (__bf16)a; x.h[1] = (__bf16)b;
  return x.u;
}

__global__ __launch_bounds__(256)
void prepack(const float* __restrict__ Kg, const float* __restrict__ Vg,
             char* __restrict__ wsK, char* __restrict__ wsV) {
  const int i = blockIdx.x * 256 + threadIdx.x;   // [0, 524288)
  {  // K pair: dp = d/2
    const int dp = i & 63, kv = (i >> 6) & (KVn - 1), bg = i >> 17;
    const float* src = Kg + ((size_t)bg * KVn + kv) * Dn + 2 * dp;
    const unsigned pr = pk2(src[0], src[1]);
    const size_t off = (size_t)bg * (KVn * 256) + (size_t)kv * 256
                       + ((4 * dp) ^ ((kv & 15) << 4));
    *(unsigned*)(wsK + off) = pr;
  }
  {  // V^T pair: (kv=2vkp, 2vkp+1) at row d, 32-kv subtile t
    const int d = i & 127, vg = (i >> 7) & 1023, bg = i >> 17;
    const int t = vg >> 4, vkp = vg & 15;
    const float* src = Vg + ((size_t)bg * KVn + t * 32 + 2 * vkp) * Dn + d;
    const unsigned pr = pk2(src[0], src[Dn]);
    const int slot = (((d >> 3) ^ (d >> 1)) & 3) << 4;
    const size_t off = ((size_t)bg * NT32 + t) * 8192 + (d << 6)
                       + ((vkp * 4) ^ slot);
    *(unsigned*)(wsV + off) = pr;
  }
}

__global__ __launch_bounds__(512, 2)
void attn_fwd(const float* __restrict__ Qg, const float* __restrict__ Mg,
              const char* __restrict__ wsK, const char* __restrict__ wsV,
              float* __restrict__ Og) {
  __shared__ __align__(16) short Ks[2][KVB * Dn];    // 8KB x2
  __shared__ __align__(16) short Vt[2][Dn * KVB];    // 8KB x2
  __shared__ __align__(16) float Ms[2][QBLK * KVB];  // 4KB x2 (swizzled rows)

  const int tid = threadIdx.x;
  const int lane = tid & 63, w = tid >> 6;           // w in [0,8)
  const int hi = lane >> 5, ln = lane & 31;
  const int qb = blockIdx.x * QBLK, ho = blockIdx.y, b = blockIdx.z;
  const int h = ho * HB + (w >> 1);                  // wave's head
  const int dh = w & 1;                              // wave's d-half
  const int g = ho >> 2, bg = b * Gn + g;            // block shares g

  // ---- Q B-fragments, PRE-SCALED: aq[ks][j] = Q[h][qb+ln][ks*16+hi*8+j]*SCALE2
  bf16x8 aq[8];
  {
    const float* qr = Qg + ((size_t)(b * Hn + h) * Qn + qb + ln) * Dn + hi * 8;
#pragma unroll
    for (int ks = 0; ks < 8; ++ks) {
      float4 f0 = *(const float4*)(qr + ks * 16);
      float4 f1 = *(const float4*)(qr + ks * 16 + 4);
      union { unsigned u[4]; bf16x8 b; } t;
      t.u[0] = pk2(f0.x * SCALE2, f0.y * SCALE2);
      t.u[1] = pk2(f0.z * SCALE2, f0.w * SCALE2);
      t.u[2] = pk2(f1.x * SCALE2, f1.y * SCALE2);
      t.u[3] = pk2(f1.z * SCALE2, f1.w * SCALE2);
      aq[ks] = t.b;
    }
  }

  const char* wsKb = wsK + (size_t)bg * (KVn * 256);
  const char* wsVb = wsV + (size_t)bg * (KVn * 256);
  // mask stage geometry (waves 0-3): wave w covers rows w*8..w*8+7 (128B each)
  const int mr = (w & 3) * 8 + (lane >> 3);          // q row within tile
  const int mc = (lane & 7) << 4;                    // 16B slot within row
  const char* mSrcBase = (const char*)Mg + (size_t)(b * Qn + qb + mr) * (KVn * 4)
                         + (mc ^ ((mr & 7) << 4));   // pre-swizzled source

  // waves 0-3: K (2 gll) + mask (1 gll); waves 4-7: V (2 gll)
  auto stage = [&](int tile, int buf) {
    if (w < 4) {
      const char* sk = wsKb + (size_t)tile * 8192 + w * 2048 + lane * 16;
      char* dk = (char*)Ks[buf] + w * 2048;
      __builtin_amdgcn_global_load_lds(
          (const __attribute__((address_space(1))) void*)sk,
          (__attribute__((address_space(3))) void*)dk, 16, 0, 0);
      __builtin_amdgcn_global_load_lds(
          (const __attribute__((address_space(1))) void*)(sk + 1024),
          (__attribute__((address_space(3))) void*)(dk + 1024), 16, 0, 0);
      const char* sm = mSrcBase + tile * 128;
      char* dm = (char*)Ms[buf] + w * 1024;
      __builtin_amdgcn_global_load_lds(
          (const __attribute__((address_space(1))) void*)sm,
          (__attribute__((address_space(3))) void*)dm, 16, 0, 0);
    } else {
      const int wv = w - 4;
      const char* sv = wsVb + (size_t)tile * 8192 + wv * 2048 + lane * 16;
      char* dv = (char*)Vt[buf] + wv * 2048;
      __builtin_amdgcn_global_load_lds(
          (const __attribute__((address_space(1))) void*)sv,
          (__attribute__((address_space(3))) void*)dv, 16, 0, 0);
      __builtin_amdgcn_global_load_lds(
          (const __attribute__((address_space(1))) void*)(sv + 1024),
          (__attribute__((address_space(3))) void*)(dv + 1024), 16, 0, 0);
    }
  };

  f32x16 o[2];   // d-half accumulator: 32 regs (the occupancy fix)
#pragma unroll
  for (int j = 0; j < 2; ++j)
#pragma unroll
    for (int e = 0; e < 16; ++e) o[j][e] = 0.0f;
  float lsum = 0.0f;

  // ---- prologue ----
  stage(0, 0);
  __syncthreads();

  const int ksw = (ln & 15) << 4;
  const int msw = (ln & 7) << 4;

  for (int t = 0; t < NT; ++t) {
    const int cur = t & 1;
    const int tn = (t + 1 < NT) ? t + 1 : t;

    stage(tn, cur ^ 1);     // prefetch next tile (gll; covered by tile body)
    __builtin_amdgcn_sched_barrier(0);

    // ---- QK^T swapped: S^T[kv][q], kv=(r&3)+8*(r>>2)+4*hi, q=ln ----
    f32x16 s;
#pragma unroll
    for (int e = 0; e < 16; ++e) s[e] = 0.0f;
    const char* ksb = (const char*)Ks[cur];
    __builtin_amdgcn_s_setprio(1);
#pragma unroll
    for (int ks = 0; ks < 8; ++ks) {
      bf16x8 k0 = *(const bf16x8*)(ksb + (ln << 8) + ((ks * 32 + hi * 16) ^ ksw));
      s = __builtin_amdgcn_mfma_f32_32x32x16_bf16(k0, aq[ks], s, 0, 0, 0);
    }
    __builtin_amdgcn_s_setprio(0);

    // ---- softmax: p = exp2(s + mk*L2E); mask from LDS (swizzled rows) ----
    const char* msb = (const char*)Ms[cur] + ln * 128;
    unsigned own[8];
    float psum = 0.0f;
#pragma unroll
    for (int gq = 0; gq < 4; ++gq) {
      float4 mkq = *(const float4*)(msb + ((gq * 32 + hi * 16) ^ msw));
      float p0 = __builtin_exp2f(__builtin_fmaf(mkq.x, L2E, s[4 * gq + 0]));
      float p1 = __builtin_exp2f(__builtin_fmaf(mkq.y, L2E, s[4 * gq + 1]));
      float p2 = __builtin_exp2f(__builtin_fmaf(mkq.z, L2E, s[4 * gq + 2]));
      float p3 = __builtin_exp2f(__builtin_fmaf(mkq.w, L2E, s[4 * gq + 3]));
      psum += (p0 + p1) + (p2 + p3);
      own[2 * gq] = pk2(p0, p1);
      own[2 * gq + 1] = pk2(p2, p3);
    }
    lsum += psum;

    // ---- P B-frags via shfl_xor (verified): pf[ks][j]=P[q][ks*16+hi*8+j] ----
    unsigned sw[8];
#pragma unroll
    for (int i = 0; i < 8; ++i) sw[i] = __shfl_xor(own[i], 32);
    union Frag { unsigned u[4]; bf16x8 b; };
    Frag pf[2];
#pragma unroll
    for (int ks = 0; ks < 2; ++ks) {
      const int bsl = ks * 4;
      pf[ks].u[0] = hi ? sw[bsl + 2] : own[bsl + 0];
      pf[ks].u[1] = hi ? sw[bsl + 3] : own[bsl + 1];
      pf[ks].u[2] = hi ? own[bsl + 2] : sw[bsl + 0];
      pf[ks].u[3] = hi ? own[bsl + 3] : sw[bsl + 1];
    }

    // ---- PV swapped (d-half only): O^T[d][q] += V^T · P ----
    const char* vtb = (const char*)Vt[cur];
    __builtin_amdgcn_s_setprio(1);
#pragma unroll
    for (int j = 0; j < 2; ++j) {
      const int d = (dh * 2 + j) * 32 + ln;
      const int swz = (((d >> 3) ^ (d >> 1)) & 3) << 4;
#pragma unroll
      for (int ks = 0; ks < 2; ++ks) {
        bf16x8 vfr = *(const bf16x8*)(vtb + (d << 6) + (((ks * 32 + hi * 16)) ^ swz));
        o[j] = __builtin_amdgcn_mfma_f32_32x32x16_bf16(vfr, pf[ks].b, o[j], 0, 0, 0);
      }
    }
    __builtin_amdgcn_s_setprio(0);

    // one barrier per tile; drains vmcnt (gll for t+1 done) + lgkmcnt
    __syncthreads();
  }

  // ---- epilogue: O^T/l, write context[q][b][h*128 + dh*64 + ...] ----
  const float ltot = lsum + __shfl_xor(lsum, 32);
  const float invl = 1.0f / ltot;
  float* outp = Og + (size_t)(qb + ln) * (Bn * Hn * Dn) + (size_t)b * (Hn * Dn) + h * Dn;
#pragma unroll
  for (int j = 0; j < 2; ++j) {
    const int nt = dh * 2 + j;
#pragma unroll
    for (int gq = 0; gq < 4; ++gq) {
      float4 v;
      v.x = o[j][gq * 4 + 0] * invl;
      v.y = o[j][gq * 4 + 1] * invl;
      v.z = o[j][gq * 4 + 2] * invl;
      v.w = o[j][gq * 4 + 3] * invl;
      *(float4*)(outp + nt * 32 + gq * 8 + hi * 4) = v;
    }
  }
}

extern "C" void kernel_launch(void* const* d_in, const int* in_sizes, int n_in,
                              void* d_out, int out_size, void* d_ws, size_t ws_size,
                              hipStream_t stream) {
  const float* q = (const float*)d_in[0];
  const float* k = (const float*)d_in[1];
  const float* v = (const float*)d_in[2];
  const float* m = (const float*)d_in[3];
  float* out = (float*)d_out;
  char* wsK = (char*)d_ws;
  char* wsV = wsK + WSK_BYTES;

  prepack<<<dim3((Bn * Gn * KVn * 64) / 256), 256, 0, stream>>>(k, v, wsK, wsV);
  dim3 grid(Qn / QBLK, Hn / HB, Bn);
  attn_fwd<<<grid, WAVES * 64, 0, stream>>>(q, m, wsK, wsV, out);
}

// Round 15
// 338.741 us; speedup vs baseline: 1.0793x; 1.0793x over previous
//
#include <hip/hip_runtime.h>
#include <hip/hip_bf16.h>

// CoreAttention (ChatGLM GQA fallback) — swapped-operand 32x32x16 bf16 MFMA
// flash attention. Round 15: r14 SPLIT-D WAVE PAIRS, single change:
// __launch_bounds__(512,4) — the only config that ever delivered >40%
// occupancy (r12). With acc=32 AGPR the arch cap is ~96 vs r14's measured 68,
// so unlike r12 (needed 84 under a 64 cap -> spill) this should fit cleanly.
// Block = 8 waves = 4 heads x 2 d-halves; full QK^T per wave (duplicated in
// pair), softmax, PV for 64 of 128 d -> o[2] = 32 AGPR.
// K/V/mask staged once per block via global_load_lds from pre-swizzled images.
// B=2, H=32, G=2, Q=KV=2048, D=128, fp32 in/out.

constexpr int Bn = 2, Hn = 32, Gn = 2, Qn = 2048, KVn = 2048, Dn = 128;
constexpr int WAVES = 8, QBLK = 32, HB = 4;           // 4 heads/block
constexpr int KVB = 32, NT = KVn / KVB;               // 64 kv tiles
constexpr int NT32 = KVn / 32;
constexpr float SCALE = 0.08838834764831843f;         // 1/sqrt(128)
constexpr float L2E = 1.4426950408889634f;
constexpr float SCALE2 = SCALE * L2E;

// ws: K images (2 MiB) then V images (2 MiB); needs ws >= 4 MiB.
constexpr size_t WSK_BYTES = (size_t)Bn * Gn * KVn * 256;   // 2 MiB

typedef __attribute__((ext_vector_type(16))) float f32x16;
typedef __attribute__((ext_vector_type(8))) __bf16 bf16x8;

__device__ __forceinline__ unsigned pk2(float a, float b) {
  union { __bf16 h[2]; unsigned u; } x;
  x.h[0] = (__bf16)a; x.h[1] = (__bf16)b;
  return x.u;
}

__global__ __launch_bounds__(256)
void prepack(const float* __restrict__ Kg, const float* __restrict__ Vg,
             char* __restrict__ wsK, char* __restrict__ wsV) {
  const int i = blockIdx.x * 256 + threadIdx.x;   // [0, 524288)
  {  // K pair: dp = d/2
    const int dp = i & 63, kv = (i >> 6) & (KVn - 1), bg = i >> 17;
    const float* src = Kg + ((size_t)bg * KVn + kv) * Dn + 2 * dp;
    const unsigned pr = pk2(src[0], src[1]);
    const size_t off = (size_t)bg * (KVn * 256) + (size_t)kv * 256
                       + ((4 * dp) ^ ((kv & 15) << 4));
    *(unsigned*)(wsK + off) = pr;
  }
  {  // V^T pair: (kv=2vkp, 2vkp+1) at row d, 32-kv subtile t
    const int d = i & 127, vg = (i >> 7) & 1023, bg = i >> 17;
    const int t = vg >> 4, vkp = vg & 15;
    const float* src = Vg + ((size_t)bg * KVn + t * 32 + 2 * vkp) * Dn + d;
    const unsigned pr = pk2(src[0], src[Dn]);
    const int slot = (((d >> 3) ^ (d >> 1)) & 3) << 4;
    const size_t off = ((size_t)bg * NT32 + t) * 8192 + (d << 6)
                       + ((vkp * 4) ^ slot);
    *(unsigned*)(wsV + off) = pr;
  }
}

__global__ __launch_bounds__(512, 4)
void attn_fwd(const float* __restrict__ Qg, const float* __restrict__ Mg,
              const char* __restrict__ wsK, const char* __restrict__ wsV,
              float* __restrict__ Og) {
  __shared__ __align__(16) short Ks[2][KVB * Dn];    // 8KB x2
  __shared__ __align__(16) short Vt[2][Dn * KVB];    // 8KB x2
  __shared__ __align__(16) float Ms[2][QBLK * KVB];  // 4KB x2 (swizzled rows)

  const int tid = threadIdx.x;
  const int lane = tid & 63, w = tid >> 6;           // w in [0,8)
  const int hi = lane >> 5, ln = lane & 31;
  const int qb = blockIdx.x * QBLK, ho = blockIdx.y, b = blockIdx.z;
  const int h = ho * HB + (w >> 1);                  // wave's head
  const int dh = w & 1;                              // wave's d-half
  const int g = ho >> 2, bg = b * Gn + g;            // block shares g

  // ---- Q B-fragments, PRE-SCALED: aq[ks][j] = Q[h][qb+ln][ks*16+hi*8+j]*SCALE2
  bf16x8 aq[8];
  {
    const float* qr = Qg + ((size_t)(b * Hn + h) * Qn + qb + ln) * Dn + hi * 8;
#pragma unroll
    for (int ks = 0; ks < 8; ++ks) {
      float4 f0 = *(const float4*)(qr + ks * 16);
      float4 f1 = *(const float4*)(qr + ks * 16 + 4);
      union { unsigned u[4]; bf16x8 b; } t;
      t.u[0] = pk2(f0.x * SCALE2, f0.y * SCALE2);
      t.u[1] = pk2(f0.z * SCALE2, f0.w * SCALE2);
      t.u[2] = pk2(f1.x * SCALE2, f1.y * SCALE2);
      t.u[3] = pk2(f1.z * SCALE2, f1.w * SCALE2);
      aq[ks] = t.b;
    }
  }

  const char* wsKb = wsK + (size_t)bg * (KVn * 256);
  const char* wsVb = wsV + (size_t)bg * (KVn * 256);
  // mask stage geometry (waves 0-3): wave w covers rows w*8..w*8+7 (128B each)
  const int mr = (w & 3) * 8 + (lane >> 3);          // q row within tile
  const int mc = (lane & 7) << 4;                    // 16B slot within row
  const char* mSrcBase = (const char*)Mg + (size_t)(b * Qn + qb + mr) * (KVn * 4)
                         + (mc ^ ((mr & 7) << 4));   // pre-swizzled source

  // waves 0-3: K (2 gll) + mask (1 gll); waves 4-7: V (2 gll)
  auto stage = [&](int tile, int buf) {
    if (w < 4) {
      const char* sk = wsKb + (size_t)tile * 8192 + w * 2048 + lane * 16;
      char* dk = (char*)Ks[buf] + w * 2048;
      __builtin_amdgcn_global_load_lds(
          (const __attribute__((address_space(1))) void*)sk,
          (__attribute__((address_space(3))) void*)dk, 16, 0, 0);
      __builtin_amdgcn_global_load_lds(
          (const __attribute__((address_space(1))) void*)(sk + 1024),
          (__attribute__((address_space(3))) void*)(dk + 1024), 16, 0, 0);
      const char* sm = mSrcBase + tile * 128;
      char* dm = (char*)Ms[buf] + w * 1024;
      __builtin_amdgcn_global_load_lds(
          (const __attribute__((address_space(1))) void*)sm,
          (__attribute__((address_space(3))) void*)dm, 16, 0, 0);
    } else {
      const int wv = w - 4;
      const char* sv = wsVb + (size_t)tile * 8192 + wv * 2048 + lane * 16;
      char* dv = (char*)Vt[buf] + wv * 2048;
      __builtin_amdgcn_global_load_lds(
          (const __attribute__((address_space(1))) void*)sv,
          (__attribute__((address_space(3))) void*)dv, 16, 0, 0);
      __builtin_amdgcn_global_load_lds(
          (const __attribute__((address_space(1))) void*)(sv + 1024),
          (__attribute__((address_space(3))) void*)(dv + 1024), 16, 0, 0);
    }
  };

  f32x16 o[2];   // d-half accumulator: 32 regs
#pragma unroll
  for (int j = 0; j < 2; ++j)
#pragma unroll
    for (int e = 0; e < 16; ++e) o[j][e] = 0.0f;
  float lsum = 0.0f;

  // ---- prologue ----
  stage(0, 0);
  __syncthreads();

  const int ksw = (ln & 15) << 4;
  const int msw = (ln & 7) << 4;

  for (int t = 0; t < NT; ++t) {
    const int cur = t & 1;
    const int tn = (t + 1 < NT) ? t + 1 : t;

    stage(tn, cur ^ 1);     // prefetch next tile (gll; covered by tile body)
    __builtin_amdgcn_sched_barrier(0);

    // ---- QK^T swapped: S^T[kv][q], kv=(r&3)+8*(r>>2)+4*hi, q=ln ----
    f32x16 s;
#pragma unroll
    for (int e = 0; e < 16; ++e) s[e] = 0.0f;
    const char* ksb = (const char*)Ks[cur];
    __builtin_amdgcn_s_setprio(1);
#pragma unroll
    for (int ks = 0; ks < 8; ++ks) {
      bf16x8 k0 = *(const bf16x8*)(ksb + (ln << 8) + ((ks * 32 + hi * 16) ^ ksw));
      s = __builtin_amdgcn_mfma_f32_32x32x16_bf16(k0, aq[ks], s, 0, 0, 0);
    }
    __builtin_amdgcn_s_setprio(0);

    // ---- softmax: p = exp2(s + mk*L2E); mask from LDS (swizzled rows) ----
    const char* msb = (const char*)Ms[cur] + ln * 128;
    unsigned own[8];
    float psum = 0.0f;
#pragma unroll
    for (int gq = 0; gq < 4; ++gq) {
      float4 mkq = *(const float4*)(msb + ((gq * 32 + hi * 16) ^ msw));
      float p0 = __builtin_exp2f(__builtin_fmaf(mkq.x, L2E, s[4 * gq + 0]));
      float p1 = __builtin_exp2f(__builtin_fmaf(mkq.y, L2E, s[4 * gq + 1]));
      float p2 = __builtin_exp2f(__builtin_fmaf(mkq.z, L2E, s[4 * gq + 2]));
      float p3 = __builtin_exp2f(__builtin_fmaf(mkq.w, L2E, s[4 * gq + 3]));
      psum += (p0 + p1) + (p2 + p3);
      own[2 * gq] = pk2(p0, p1);
      own[2 * gq + 1] = pk2(p2, p3);
    }
    lsum += psum;

    // ---- P B-frags via shfl_xor (verified): pf[ks][j]=P[q][ks*16+hi*8+j] ----
    unsigned sw[8];
#pragma unroll
    for (int i = 0; i < 8; ++i) sw[i] = __shfl_xor(own[i], 32);
    union Frag { unsigned u[4]; bf16x8 b; };
    Frag pf[2];
#pragma unroll
    for (int ks = 0; ks < 2; ++ks) {
      const int bsl = ks * 4;
      pf[ks].u[0] = hi ? sw[bsl + 2] : own[bsl + 0];
      pf[ks].u[1] = hi ? sw[bsl + 3] : own[bsl + 1];
      pf[ks].u[2] = hi ? own[bsl + 2] : sw[bsl + 0];
      pf[ks].u[3] = hi ? own[bsl + 3] : sw[bsl + 1];
    }

    // ---- PV swapped (d-half only): O^T[d][q] += V^T · P ----
    const char* vtb = (const char*)Vt[cur];
    __builtin_amdgcn_s_setprio(1);
#pragma unroll
    for (int j = 0; j < 2; ++j) {
      const int d = (dh * 2 + j) * 32 + ln;
      const int swz = (((d >> 3) ^ (d >> 1)) & 3) << 4;
#pragma unroll
      for (int ks = 0; ks < 2; ++ks) {
        bf16x8 vfr = *(const bf16x8*)(vtb + (d << 6) + (((ks * 32 + hi * 16)) ^ swz));
        o[j] = __builtin_amdgcn_mfma_f32_32x32x16_bf16(vfr, pf[ks].b, o[j], 0, 0, 0);
      }
    }
    __builtin_amdgcn_s_setprio(0);

    // one barrier per tile; drains vmcnt (gll for t+1 done) + lgkmcnt
    __syncthreads();
  }

  // ---- epilogue: O^T/l, write context[q][b][h*128 + dh*64 + ...] ----
  const float ltot = lsum + __shfl_xor(lsum, 32);
  const float invl = 1.0f / ltot;
  float* outp = Og + (size_t)(qb + ln) * (Bn * Hn * Dn) + (size_t)b * (Hn * Dn) + h * Dn;
#pragma unroll
  for (int j = 0; j < 2; ++j) {
    const int nt = dh * 2 + j;
#pragma unroll
    for (int gq = 0; gq < 4; ++gq) {
      float4 v;
      v.x = o[j][gq * 4 + 0] * invl;
      v.y = o[j][gq * 4 + 1] * invl;
      v.z = o[j][gq * 4 + 2] * invl;
      v.w = o[j][gq * 4 + 3] * invl;
      *(float4*)(outp + nt * 32 + gq * 8 + hi * 4) = v;
    }
  }
}

extern "C" void kernel_launch(void* const* d_in, const int* in_sizes, int n_in,
                              void* d_out, int out_size, void* d_ws, size_t ws_size,
                              hipStream_t stream) {
  const float* q = (const float*)d_in[0];
  const float* k = (const float*)d_in[1];
  const float* v = (const float*)d_in[2];
  const float* m = (const float*)d_in[3];
  float* out = (float*)d_out;
  char* wsK = (char*)d_ws;
  char* wsV = wsK + WSK_BYTES;

  prepack<<<dim3((Bn * Gn * KVn * 64) / 256), 256, 0, stream>>>(k, v, wsK, wsV);
  dim3 grid(Qn / QBLK, Hn / HB, Bn);
  attn_fwd<<<grid, WAVES * 64, 0, stream>>>(q, m, wsK, wsV, out);
}

// Round 16
// 228.268 us; speedup vs baseline: 1.6016x; 1.4840x over previous
//
#include <hip/hip_runtime.h>
#include <hip/hip_bf16.h>

// CoreAttention (ChatGLM GQA fallback) — swapped-operand 32x32x16 bf16 MFMA
// flash attention. Round 16: r13 head-octet structure (8 waves = 8 heads
// sharing K/V/mask LDS tiles, gll-staged from pre-swizzled images) with
// KVB=64 (half the barriers/tile-fixed-costs; r10-verified math) and
// permlane32_swap P-fragment assembly (replaces 8 ds_bpermute + 16 cndmask).
// Occupancy arc r12-r15 closed: 4 waves/SIMD gave no per-work gain; this
// round cuts per-tile overhead and LDS-pipe ops instead.
// B=2, H=32, G=2, Q=KV=2048, D=128, fp32 in/out.

constexpr int Bn = 2, Hn = 32, Gn = 2, Qn = 2048, KVn = 2048, Dn = 128;
constexpr int WAVES = 8, QBLK = 32, HO = 8;           // 8 heads/block
constexpr int KVB = 64, NT = KVn / KVB;               // 32 kv tiles of 64
constexpr int NT32 = KVn / 32;
constexpr float SCALE = 0.08838834764831843f;         // 1/sqrt(128)
constexpr float L2E = 1.4426950408889634f;
constexpr float SCALE2 = SCALE * L2E;

constexpr size_t WSK_BYTES = (size_t)Bn * Gn * KVn * 256;   // 2 MiB

typedef __attribute__((ext_vector_type(16))) float f32x16;
typedef __attribute__((ext_vector_type(8))) __bf16 bf16x8;
typedef __attribute__((ext_vector_type(2))) unsigned u32x2;

__device__ __forceinline__ unsigned pk2(float a, float b) {
  union { __bf16 h[2]; unsigned u; } x;
  x.h[0] = (__bf16)a; x.h[1] = (__bf16)b;
  return x.u;
}

__global__ __launch_bounds__(256)
void prepack(const float* __restrict__ Kg, const float* __restrict__ Vg,
             char* __restrict__ wsK, char* __restrict__ wsV) {
  const int i = blockIdx.x * 256 + threadIdx.x;   // [0, 524288)
  {  // K pair: dp = d/2
    const int dp = i & 63, kv = (i >> 6) & (KVn - 1), bg = i >> 17;
    const float* src = Kg + ((size_t)bg * KVn + kv) * Dn + 2 * dp;
    const unsigned pr = pk2(src[0], src[1]);
    const size_t off = (size_t)bg * (KVn * 256) + (size_t)kv * 256
                       + ((4 * dp) ^ ((kv & 15) << 4));
    *(unsigned*)(wsK + off) = pr;
  }
  {  // V^T pair: (kv=2vkp, 2vkp+1) at row d, 32-kv subtile t
    const int d = i & 127, vg = (i >> 7) & 1023, bg = i >> 17;
    const int t = vg >> 4, vkp = vg & 15;
    const float* src = Vg + ((size_t)bg * KVn + t * 32 + 2 * vkp) * Dn + d;
    const unsigned pr = pk2(src[0], src[Dn]);
    const int slot = (((d >> 3) ^ (d >> 1)) & 3) << 4;
    const size_t off = ((size_t)bg * NT32 + t) * 8192 + (d << 6)
                       + ((vkp * 4) ^ slot);
    *(unsigned*)(wsV + off) = pr;
  }
}

__global__ __launch_bounds__(512, 2)
void attn_fwd(const float* __restrict__ Qg, const float* __restrict__ Mg,
              const char* __restrict__ wsK, const char* __restrict__ wsV,
              float* __restrict__ Og) {
  __shared__ __align__(16) short Ks[2][KVB * Dn];    // 16KB x2
  __shared__ __align__(16) short Vt[2][Dn * KVB];    // 16KB x2
  __shared__ __align__(16) float Ms[2][QBLK * KVB];  // 8KB x2 (swizzled rows)

  const int tid = threadIdx.x;
  const int lane = tid & 63, w = tid >> 6;           // w in [0,8)
  const int hi = lane >> 5, ln = lane & 31;
  const int qb = blockIdx.x * QBLK, ho = blockIdx.y, b = blockIdx.z;
  const int h = ho * HO + w;                         // wave's head
  const int g = ho >> 1, bg = b * Gn + g;            // octet shares g

  // ---- Q B-fragments, PRE-SCALED: aq[ks][j] = Q[h][qb+ln][ks*16+hi*8+j]*SCALE2
  bf16x8 aq[8];
  {
    const float* qr = Qg + ((size_t)(b * Hn + h) * Qn + qb + ln) * Dn + hi * 8;
#pragma unroll
    for (int ks = 0; ks < 8; ++ks) {
      float4 f0 = *(const float4*)(qr + ks * 16);
      float4 f1 = *(const float4*)(qr + ks * 16 + 4);
      union { unsigned u[4]; bf16x8 b; } t;
      t.u[0] = pk2(f0.x * SCALE2, f0.y * SCALE2);
      t.u[1] = pk2(f0.z * SCALE2, f0.w * SCALE2);
      t.u[2] = pk2(f1.x * SCALE2, f1.y * SCALE2);
      t.u[3] = pk2(f1.z * SCALE2, f1.w * SCALE2);
      aq[ks] = t.b;
    }
  }

  const char* wsKb = wsK + (size_t)bg * (KVn * 256);
  const char* wsVb = wsV + (size_t)bg * (KVn * 256);
  // mask stage geometry: wave w covers rows w*4..w*4+3 (256B each)
  const int mr = w * 4 + (lane >> 4);                // q row within tile
  const int mc = (lane & 15) << 4;                   // 16B slot within row
  const char* mSrcBase = (const char*)Mg + (size_t)(b * Qn + qb + mr) * (KVn * 4)
                         + (mc ^ ((mr & 15) << 4));  // pre-swizzled source

  // every wave: K 2 gll + V 2 gll + mask 1 gll (each 1024B/wave)
  auto stage = [&](int tile, int buf) {
    const char* sk = wsKb + (size_t)tile * 16384 + w * 2048 + lane * 16;
    char* dk = (char*)Ks[buf] + w * 2048;
    __builtin_amdgcn_global_load_lds(
        (const __attribute__((address_space(1))) void*)sk,
        (__attribute__((address_space(3))) void*)dk, 16, 0, 0);
    __builtin_amdgcn_global_load_lds(
        (const __attribute__((address_space(1))) void*)(sk + 1024),
        (__attribute__((address_space(3))) void*)(dk + 1024), 16, 0, 0);
    const char* sv = wsVb + (size_t)tile * 16384 + w * 2048 + lane * 16;
    char* dv = (char*)Vt[buf] + w * 2048;
    __builtin_amdgcn_global_load_lds(
        (const __attribute__((address_space(1))) void*)sv,
        (__attribute__((address_space(3))) void*)dv, 16, 0, 0);
    __builtin_amdgcn_global_load_lds(
        (const __attribute__((address_space(1))) void*)(sv + 1024),
        (__attribute__((address_space(3))) void*)(dv + 1024), 16, 0, 0);
    const char* sm = mSrcBase + tile * 256;
    char* dm = (char*)Ms[buf] + w * 1024;
    __builtin_amdgcn_global_load_lds(
        (const __attribute__((address_space(1))) void*)sm,
        (__attribute__((address_space(3))) void*)dm, 16, 0, 0);
  };

  f32x16 o[4];
#pragma unroll
  for (int nt = 0; nt < 4; ++nt)
#pragma unroll
    for (int e = 0; e < 16; ++e) o[nt][e] = 0.0f;
  float lsum = 0.0f;

  // ---- prologue ----
  stage(0, 0);
  __syncthreads();

  const int ksw = (ln & 15) << 4;
  const int msw = (ln & 15) << 4;

  for (int t = 0; t < NT; ++t) {
    const int cur = t & 1;
    const int tn = (t + 1 < NT) ? t + 1 : t;

    stage(tn, cur ^ 1);     // prefetch next tile (gll; covered by tile body)
    __builtin_amdgcn_sched_barrier(0);

    // ---- QK^T swapped (two kv sub-tiles): S^T[kv][q], q=ln ----
    f32x16 s0, s1;
#pragma unroll
    for (int e = 0; e < 16; ++e) { s0[e] = 0.0f; s1[e] = 0.0f; }
    const char* ksb = (const char*)Ks[cur];
    __builtin_amdgcn_s_setprio(1);
#pragma unroll
    for (int ks = 0; ks < 8; ++ks) {
      const int byte = (ks * 32 + hi * 16) ^ ksw;
      bf16x8 k0 = *(const bf16x8*)(ksb + (ln << 8) + byte);
      bf16x8 k1 = *(const bf16x8*)(ksb + ((32 + ln) << 8) + byte);
      s0 = __builtin_amdgcn_mfma_f32_32x32x16_bf16(k0, aq[ks], s0, 0, 0, 0);
      s1 = __builtin_amdgcn_mfma_f32_32x32x16_bf16(k1, aq[ks], s1, 0, 0, 0);
    }
    __builtin_amdgcn_s_setprio(0);

    // ---- softmax: p = exp2(s + mk*L2E); mask from LDS (swizzled 256B rows) ----
    const char* msb = (const char*)Ms[cur] + ln * 256;
    unsigned own0[8], own1[8];
    float psum = 0.0f;
#pragma unroll
    for (int gq = 0; gq < 4; ++gq) {
      float4 m0 = *(const float4*)(msb + ((gq * 32 + hi * 16) ^ msw));
      float4 m1 = *(const float4*)(msb + ((128 + gq * 32 + hi * 16) ^ msw));
      float p0 = __builtin_exp2f(__builtin_fmaf(m0.x, L2E, s0[4 * gq + 0]));
      float p1 = __builtin_exp2f(__builtin_fmaf(m0.y, L2E, s0[4 * gq + 1]));
      float p2 = __builtin_exp2f(__builtin_fmaf(m0.z, L2E, s0[4 * gq + 2]));
      float p3 = __builtin_exp2f(__builtin_fmaf(m0.w, L2E, s0[4 * gq + 3]));
      float q0 = __builtin_exp2f(__builtin_fmaf(m1.x, L2E, s1[4 * gq + 0]));
      float q1 = __builtin_exp2f(__builtin_fmaf(m1.y, L2E, s1[4 * gq + 1]));
      float q2 = __builtin_exp2f(__builtin_fmaf(m1.z, L2E, s1[4 * gq + 2]));
      float q3 = __builtin_exp2f(__builtin_fmaf(m1.w, L2E, s1[4 * gq + 3]));
      psum += ((p0 + p1) + (p2 + p3)) + ((q0 + q1) + (q2 + q3));
      own0[2 * gq] = pk2(p0, p1); own0[2 * gq + 1] = pk2(p2, p3);
      own1[2 * gq] = pk2(q0, q1); own1[2 * gq + 1] = pk2(q2, q3);
    }
    lsum += psum;

    // ---- P B-frags: pf[ks][j] = P[q][ks*16+hi*8+j] ----
    union Frag { unsigned u[4]; bf16x8 b; };
    Frag pf[4];
#pragma unroll
    for (int ks = 0; ks < 4; ++ks) {
      const unsigned* ow = (ks < 2) ? own0 : own1;
      const int bsl = (ks & 1) * 4;
#if __has_builtin(__builtin_amdgcn_permlane32_swap)
      u32x2 r0 = __builtin_amdgcn_permlane32_swap(ow[bsl + 0], ow[bsl + 2], false, false);
      u32x2 r1 = __builtin_amdgcn_permlane32_swap(ow[bsl + 1], ow[bsl + 3], false, false);
      pf[ks].u[0] = r0.x; pf[ks].u[2] = r0.y;
      pf[ks].u[1] = r1.x; pf[ks].u[3] = r1.y;
#else
      unsigned sA = __shfl_xor(ow[bsl + 0], 32), sC = __shfl_xor(ow[bsl + 2], 32);
      unsigned sB = __shfl_xor(ow[bsl + 1], 32), sD = __shfl_xor(ow[bsl + 3], 32);
      pf[ks].u[0] = hi ? sC : ow[bsl + 0];
      pf[ks].u[1] = hi ? sD : ow[bsl + 1];
      pf[ks].u[2] = hi ? ow[bsl + 2] : sA;
      pf[ks].u[3] = hi ? ow[bsl + 3] : sB;
#endif
    }

    // ---- PV swapped: O^T[d][q] += V^T · P (ks 0,1 sub0; 2,3 sub1) ----
    const char* vtb = (const char*)Vt[cur];
    __builtin_amdgcn_s_setprio(1);
#pragma unroll
    for (int nt = 0; nt < 4; ++nt) {
      const int d = nt * 32 + ln;
      const int swz = (((d >> 3) ^ (d >> 1)) & 3) << 4;
#pragma unroll
      for (int ks = 0; ks < 4; ++ks) {
        const int base = (ks >> 1) * 8192 + (d << 6);
        bf16x8 vfr = *(const bf16x8*)(vtb + base + (((ks & 1) * 32 + hi * 16) ^ swz));
        o[nt] = __builtin_amdgcn_mfma_f32_32x32x16_bf16(vfr, pf[ks].b, o[nt], 0, 0, 0);
      }
    }
    __builtin_amdgcn_s_setprio(0);

    // one barrier per tile; drains vmcnt (gll for t+1 done) + lgkmcnt
    __syncthreads();
  }

  // ---- epilogue: O^T/l, write context[q][b][h*128+d] ----
  const float ltot = lsum + __shfl_xor(lsum, 32);
  const float invl = 1.0f / ltot;
  float* outp = Og + (size_t)(qb + ln) * (Bn * Hn * Dn) + (size_t)b * (Hn * Dn) + h * Dn;
#pragma unroll
  for (int nt = 0; nt < 4; ++nt)
#pragma unroll
    for (int gq = 0; gq < 4; ++gq) {
      float4 v;
      v.x = o[nt][gq * 4 + 0] * invl;
      v.y = o[nt][gq * 4 + 1] * invl;
      v.z = o[nt][gq * 4 + 2] * invl;
      v.w = o[nt][gq * 4 + 3] * invl;
      *(float4*)(outp + nt * 32 + gq * 8 + hi * 4) = v;
    }
}

extern "C" void kernel_launch(void* const* d_in, const int* in_sizes, int n_in,
                              void* d_out, int out_size, void* d_ws, size_t ws_size,
                              hipStream_t stream) {
  const float* q = (const float*)d_in[0];
  const float* k = (const float*)d_in[1];
  const float* v = (const float*)d_in[2];
  const float* m = (const float*)d_in[3];
  float* out = (float*)d_out;
  char* wsK = (char*)d_ws;
  char* wsV = wsK + WSK_BYTES;

  prepack<<<dim3((Bn * Gn * KVn * 64) / 256), 256, 0, stream>>>(k, v, wsK, wsV);
  dim3 grid(Qn / QBLK, Hn / HO, Bn);
  attn_fwd<<<grid, WAVES * 64, 0, stream>>>(q, m, wsK, wsV, out);
}

// Round 17
// 219.474 us; speedup vs baseline: 1.6658x; 1.0401x over previous
//
#include <hip/hip_runtime.h>
#include <hip/hip_bf16.h>

// CoreAttention (ChatGLM GQA fallback) — swapped-operand 32x32x16 bf16 MFMA
// flash attention. Round 17: 2-STAGE SOFTWARE PIPELINE on r16's head-octet
// structure: each body computes QK^T(t+1)->sN while softmax+PV(t) consumes sC
// (independent -> MFMA co-issues with VALU instead of serializing; the
// cross-round invariant MfmaUtil*dur showed we were dependency-chain bound).
// K staged 2 ahead (2 buf), V/M staged 1 ahead (2 buf); one barrier per tile;
// s ping-pong via manually unrolled x2 loop (static reg indexing, rule 20).
// B=2, H=32, G=2, Q=KV=2048, D=128, fp32 in/out.

constexpr int Bn = 2, Hn = 32, Gn = 2, Qn = 2048, KVn = 2048, Dn = 128;
constexpr int WAVES = 8, QBLK = 32, HO = 8;           // 8 heads/block
constexpr int KVB = 64, NT = KVn / KVB;               // 32 kv tiles of 64
constexpr int NT32 = KVn / 32;
constexpr float SCALE = 0.08838834764831843f;         // 1/sqrt(128)
constexpr float L2E = 1.4426950408889634f;
constexpr float SCALE2 = SCALE * L2E;

constexpr size_t WSK_BYTES = (size_t)Bn * Gn * KVn * 256;   // 2 MiB

typedef __attribute__((ext_vector_type(16))) float f32x16;
typedef __attribute__((ext_vector_type(8))) __bf16 bf16x8;
typedef __attribute__((ext_vector_type(2))) unsigned u32x2;

__device__ __forceinline__ unsigned pk2(float a, float b) {
  union { __bf16 h[2]; unsigned u; } x;
  x.h[0] = (__bf16)a; x.h[1] = (__bf16)b;
  return x.u;
}

__global__ __launch_bounds__(256)
void prepack(const float* __restrict__ Kg, const float* __restrict__ Vg,
             char* __restrict__ wsK, char* __restrict__ wsV) {
  const int i = blockIdx.x * 256 + threadIdx.x;   // [0, 524288)
  {  // K pair: dp = d/2
    const int dp = i & 63, kv = (i >> 6) & (KVn - 1), bg = i >> 17;
    const float* src = Kg + ((size_t)bg * KVn + kv) * Dn + 2 * dp;
    const unsigned pr = pk2(src[0], src[1]);
    const size_t off = (size_t)bg * (KVn * 256) + (size_t)kv * 256
                       + ((4 * dp) ^ ((kv & 15) << 4));
    *(unsigned*)(wsK + off) = pr;
  }
  {  // V^T pair: (kv=2vkp, 2vkp+1) at row d, 32-kv subtile t
    const int d = i & 127, vg = (i >> 7) & 1023, bg = i >> 17;
    const int t = vg >> 4, vkp = vg & 15;
    const float* src = Vg + ((size_t)bg * KVn + t * 32 + 2 * vkp) * Dn + d;
    const unsigned pr = pk2(src[0], src[Dn]);
    const int slot = (((d >> 3) ^ (d >> 1)) & 3) << 4;
    const size_t off = ((size_t)bg * NT32 + t) * 8192 + (d << 6)
                       + ((vkp * 4) ^ slot);
    *(unsigned*)(wsV + off) = pr;
  }
}

__global__ __launch_bounds__(512, 2)
void attn_fwd(const float* __restrict__ Qg, const float* __restrict__ Mg,
              const char* __restrict__ wsK, const char* __restrict__ wsV,
              float* __restrict__ Og) {
  __shared__ __align__(16) short Ks[2][KVB * Dn];    // 16KB x2
  __shared__ __align__(16) short Vt[2][Dn * KVB];    // 16KB x2
  __shared__ __align__(16) float Ms[2][QBLK * KVB];  // 8KB x2 (swizzled rows)

  const int tid = threadIdx.x;
  const int lane = tid & 63, w = tid >> 6;           // w in [0,8)
  const int hi = lane >> 5, ln = lane & 31;
  const int qb = blockIdx.x * QBLK, ho = blockIdx.y, b = blockIdx.z;
  const int h = ho * HO + w;                         // wave's head
  const int g = ho >> 1, bg = b * Gn + g;            // octet shares g

  // ---- Q B-fragments, PRE-SCALED: aq[ks][j] = Q[h][qb+ln][ks*16+hi*8+j]*SCALE2
  bf16x8 aq[8];
  {
    const float* qr = Qg + ((size_t)(b * Hn + h) * Qn + qb + ln) * Dn + hi * 8;
#pragma unroll
    for (int ks = 0; ks < 8; ++ks) {
      float4 f0 = *(const float4*)(qr + ks * 16);
      float4 f1 = *(const float4*)(qr + ks * 16 + 4);
      union { unsigned u[4]; bf16x8 b; } t;
      t.u[0] = pk2(f0.x * SCALE2, f0.y * SCALE2);
      t.u[1] = pk2(f0.z * SCALE2, f0.w * SCALE2);
      t.u[2] = pk2(f1.x * SCALE2, f1.y * SCALE2);
      t.u[3] = pk2(f1.z * SCALE2, f1.w * SCALE2);
      aq[ks] = t.b;
    }
  }

  const char* wsKb = wsK + (size_t)bg * (KVn * 256);
  const char* wsVb = wsV + (size_t)bg * (KVn * 256);
  const int mr = w * 4 + (lane >> 4);                // q row within tile
  const int mc = (lane & 15) << 4;                   // 16B slot within row
  const char* mSrcBase = (const char*)Mg + (size_t)(b * Qn + qb + mr) * (KVn * 4)
                         + (mc ^ ((mr & 15) << 4));  // pre-swizzled source

  auto stageK = [&](int tile, int buf) {
    const char* sk = wsKb + (size_t)tile * 16384 + w * 2048 + lane * 16;
    char* dk = (char*)Ks[buf] + w * 2048;
    __builtin_amdgcn_global_load_lds(
        (const __attribute__((address_space(1))) void*)sk,
        (__attribute__((address_space(3))) void*)dk, 16, 0, 0);
    __builtin_amdgcn_global_load_lds(
        (const __attribute__((address_space(1))) void*)(sk + 1024),
        (__attribute__((address_space(3))) void*)(dk + 1024), 16, 0, 0);
  };
  auto stageVM = [&](int tile, int buf) {
    const char* sv = wsVb + (size_t)tile * 16384 + w * 2048 + lane * 16;
    char* dv = (char*)Vt[buf] + w * 2048;
    __builtin_amdgcn_global_load_lds(
        (const __attribute__((address_space(1))) void*)sv,
        (__attribute__((address_space(3))) void*)dv, 16, 0, 0);
    __builtin_amdgcn_global_load_lds(
        (const __attribute__((address_space(1))) void*)(sv + 1024),
        (__attribute__((address_space(3))) void*)(dv + 1024), 16, 0, 0);
    const char* sm = mSrcBase + tile * 256;
    char* dm = (char*)Ms[buf] + w * 1024;
    __builtin_amdgcn_global_load_lds(
        (const __attribute__((address_space(1))) void*)sm,
        (__attribute__((address_space(3))) void*)dm, 16, 0, 0);
  };

  const int ksw = (ln & 15) << 4;
  const int msw = (ln & 15) << 4;

  auto qk = [&](int buf, f32x16& t0, f32x16& t1) {
#pragma unroll
    for (int e = 0; e < 16; ++e) { t0[e] = 0.0f; t1[e] = 0.0f; }
    const char* ksb = (const char*)Ks[buf];
    __builtin_amdgcn_s_setprio(1);
#pragma unroll
    for (int ks = 0; ks < 8; ++ks) {
      const int byte = (ks * 32 + hi * 16) ^ ksw;
      bf16x8 k0 = *(const bf16x8*)(ksb + (ln << 8) + byte);
      bf16x8 k1 = *(const bf16x8*)(ksb + ((32 + ln) << 8) + byte);
      t0 = __builtin_amdgcn_mfma_f32_32x32x16_bf16(k0, aq[ks], t0, 0, 0, 0);
      t1 = __builtin_amdgcn_mfma_f32_32x32x16_bf16(k1, aq[ks], t1, 0, 0, 0);
    }
    __builtin_amdgcn_s_setprio(0);
  };

  f32x16 o[4];
#pragma unroll
  for (int nt = 0; nt < 4; ++nt)
#pragma unroll
    for (int e = 0; e < 16; ++e) o[nt][e] = 0.0f;
  float lsum = 0.0f;

  // softmax(t) from sC + PV(t); body also stages K(t+2), VM(t+1), QK(t+1)->sN
  auto body = [&](int t, f32x16& sC0, f32x16& sC1, f32x16& sN0, f32x16& sN1) {
    const int cur = t & 1, nxt = cur ^ 1;
    const int tK = (t + 2 < NT) ? t + 2 : NT - 1;
    const int tV = (t + 1 < NT) ? t + 1 : NT - 1;

    stageK(tK, cur);        // K(t+2) -> Kb[t&1]   (K(t) was read last body)
    stageVM(tV, nxt);       // V/M(t+1) -> buf[nxt] (V/M(t-1) read last body)
    __builtin_amdgcn_sched_barrier(0);

    qk(nxt, sN0, sN1);      // QK(t+1) from Kb[(t+1)&1] — independent of sC

    // ---- softmax(t): p = exp2(sC + mk*L2E) ----
    const char* msb = (const char*)Ms[cur] + ln * 256;
    unsigned own0[8], own1[8];
    float psum = 0.0f;
#pragma unroll
    for (int gq = 0; gq < 4; ++gq) {
      float4 m0 = *(const float4*)(msb + ((gq * 32 + hi * 16) ^ msw));
      float4 m1 = *(const float4*)(msb + ((128 + gq * 32 + hi * 16) ^ msw));
      float p0 = __builtin_exp2f(__builtin_fmaf(m0.x, L2E, sC0[4 * gq + 0]));
      float p1 = __builtin_exp2f(__builtin_fmaf(m0.y, L2E, sC0[4 * gq + 1]));
      float p2 = __builtin_exp2f(__builtin_fmaf(m0.z, L2E, sC0[4 * gq + 2]));
      float p3 = __builtin_exp2f(__builtin_fmaf(m0.w, L2E, sC0[4 * gq + 3]));
      float q0 = __builtin_exp2f(__builtin_fmaf(m1.x, L2E, sC1[4 * gq + 0]));
      float q1 = __builtin_exp2f(__builtin_fmaf(m1.y, L2E, sC1[4 * gq + 1]));
      float q2 = __builtin_exp2f(__builtin_fmaf(m1.z, L2E, sC1[4 * gq + 2]));
      float q3 = __builtin_exp2f(__builtin_fmaf(m1.w, L2E, sC1[4 * gq + 3]));
      psum += ((p0 + p1) + (p2 + p3)) + ((q0 + q1) + (q2 + q3));
      own0[2 * gq] = pk2(p0, p1); own0[2 * gq + 1] = pk2(p2, p3);
      own1[2 * gq] = pk2(q0, q1); own1[2 * gq + 1] = pk2(q2, q3);
    }
    lsum += psum;

    // ---- P B-frags (permlane32_swap; r16-verified) ----
    union Frag { unsigned u[4]; bf16x8 b; };
    Frag pf[4];
#pragma unroll
    for (int ks = 0; ks < 4; ++ks) {
      const unsigned* ow = (ks < 2) ? own0 : own1;
      const int bsl = (ks & 1) * 4;
#if __has_builtin(__builtin_amdgcn_permlane32_swap)
      u32x2 r0 = __builtin_amdgcn_permlane32_swap(ow[bsl + 0], ow[bsl + 2], false, false);
      u32x2 r1 = __builtin_amdgcn_permlane32_swap(ow[bsl + 1], ow[bsl + 3], false, false);
      pf[ks].u[0] = r0.x; pf[ks].u[2] = r0.y;
      pf[ks].u[1] = r1.x; pf[ks].u[3] = r1.y;
#else
      unsigned sA = __shfl_xor(ow[bsl + 0], 32), sCx = __shfl_xor(ow[bsl + 2], 32);
      unsigned sB = __shfl_xor(ow[bsl + 1], 32), sD = __shfl_xor(ow[bsl + 3], 32);
      pf[ks].u[0] = hi ? sCx : ow[bsl + 0];
      pf[ks].u[1] = hi ? sD : ow[bsl + 1];
      pf[ks].u[2] = hi ? ow[bsl + 2] : sA;
      pf[ks].u[3] = hi ? ow[bsl + 3] : sB;
#endif
    }

    // ---- PV(t): O^T[d][q] += V^T · P ----
    const char* vtb = (const char*)Vt[cur];
    __builtin_amdgcn_s_setprio(1);
#pragma unroll
    for (int nt = 0; nt < 4; ++nt) {
      const int d = nt * 32 + ln;
      const int swz = (((d >> 3) ^ (d >> 1)) & 3) << 4;
#pragma unroll
      for (int ks = 0; ks < 4; ++ks) {
        const int base = (ks >> 1) * 8192 + (d << 6);
        bf16x8 vfr = *(const bf16x8*)(vtb + base + (((ks & 1) * 32 + hi * 16) ^ swz));
        o[nt] = __builtin_amdgcn_mfma_f32_32x32x16_bf16(vfr, pf[ks].b, o[nt], 0, 0, 0);
      }
    }
    __builtin_amdgcn_s_setprio(0);

    // one barrier per tile: all gll landed, all LDS reads of old bufs done
    __syncthreads();
  };

  // ---- prologue: K(0)->Kb[0], K(1)->Kb[1], V/M(0)->buf0; QK(0)->sA ----
  stageK(0, 0);
  stageK(1, 1);
  stageVM(0, 0);
  __syncthreads();
  f32x16 sA0, sA1, sB0, sB1;
  qk(0, sA0, sA1);
  __syncthreads();   // all waves done reading Kb[0] before body(0) restages it

  for (int t = 0; t < NT; t += 2) {
    body(t, sA0, sA1, sB0, sB1);
    body(t + 1, sB0, sB1, sA0, sA1);
  }

  // ---- epilogue: O^T/l, write context[q][b][h*128+d] ----
  const float ltot = lsum + __shfl_xor(lsum, 32);
  const float invl = 1.0f / ltot;
  float* outp = Og + (size_t)(qb + ln) * (Bn * Hn * Dn) + (size_t)b * (Hn * Dn) + h * Dn;
#pragma unroll
  for (int nt = 0; nt < 4; ++nt)
#pragma unroll
    for (int gq = 0; gq < 4; ++gq) {
      float4 v;
      v.x = o[nt][gq * 4 + 0] * invl;
      v.y = o[nt][gq * 4 + 1] * invl;
      v.z = o[nt][gq * 4 + 2] * invl;
      v.w = o[nt][gq * 4 + 3] * invl;
      *(float4*)(outp + nt * 32 + gq * 8 + hi * 4) = v;
    }
}

extern "C" void kernel_launch(void* const* d_in, const int* in_sizes, int n_in,
                              void* d_out, int out_size, void* d_ws, size_t ws_size,
                              hipStream_t stream) {
  const float* q = (const float*)d_in[0];
  const float* k = (const float*)d_in[1];
  const float* v = (const float*)d_in[2];
  const float* m = (const float*)d_in[3];
  float* out = (float*)d_out;
  char* wsK = (char*)d_ws;
  char* wsV = wsK + WSK_BYTES;

  prepack<<<dim3((Bn * Gn * KVn * 64) / 256), 256, 0, stream>>>(k, v, wsK, wsV);
  dim3 grid(Qn / QBLK, Hn / HO, Bn);
  attn_fwd<<<grid, WAVES * 64, 0, stream>>>(q, m, wsK, wsV, out);
}

// Round 18
// 214.814 us; speedup vs baseline: 1.7019x; 1.0217x over previous
//
#include <hip/hip_runtime.h>
#include <hip/hip_bf16.h>

// CoreAttention (ChatGLM GQA fallback) — swapped-operand 32x32x16 bf16 MFMA
// flash attention. Round 18: r17 2-stage pipeline + overhead trim:
// incremental staging pointers (no per-tile addr recompute), softmax-first
// body ordering (VALU chain exposed early; QK(t+1) MFMAs fill its slots).
// Head-octet blocks: 8 waves = 8 heads sharing K/V/mask LDS tiles staged via
// global_load_lds from pre-swizzled bf16 images (prepack kernel, d_ws).
// B=2, H=32, G=2, Q=KV=2048, D=128, fp32 in/out.

constexpr int Bn = 2, Hn = 32, Gn = 2, Qn = 2048, KVn = 2048, Dn = 128;
constexpr int WAVES = 8, QBLK = 32, HO = 8;           // 8 heads/block
constexpr int KVB = 64, NT = KVn / KVB;               // 32 kv tiles of 64
constexpr int NT32 = KVn / 32;
constexpr float SCALE = 0.08838834764831843f;         // 1/sqrt(128)
constexpr float L2E = 1.4426950408889634f;
constexpr float SCALE2 = SCALE * L2E;

constexpr size_t WSK_BYTES = (size_t)Bn * Gn * KVn * 256;   // 2 MiB

typedef __attribute__((ext_vector_type(16))) float f32x16;
typedef __attribute__((ext_vector_type(8))) __bf16 bf16x8;
typedef __attribute__((ext_vector_type(2))) unsigned u32x2;

__device__ __forceinline__ unsigned pk2(float a, float b) {
  union { __bf16 h[2]; unsigned u; } x;
  x.h[0] = (__bf16)a; x.h[1] = (__bf16)b;
  return x.u;
}

__global__ __launch_bounds__(256)
void prepack(const float* __restrict__ Kg, const float* __restrict__ Vg,
             char* __restrict__ wsK, char* __restrict__ wsV) {
  const int i = blockIdx.x * 256 + threadIdx.x;   // [0, 524288)
  {  // K pair: dp = d/2
    const int dp = i & 63, kv = (i >> 6) & (KVn - 1), bg = i >> 17;
    const float* src = Kg + ((size_t)bg * KVn + kv) * Dn + 2 * dp;
    const unsigned pr = pk2(src[0], src[1]);
    const size_t off = (size_t)bg * (KVn * 256) + (size_t)kv * 256
                       + ((4 * dp) ^ ((kv & 15) << 4));
    *(unsigned*)(wsK + off) = pr;
  }
  {  // V^T pair: (kv=2vkp, 2vkp+1) at row d, 32-kv subtile t
    const int d = i & 127, vg = (i >> 7) & 1023, bg = i >> 17;
    const int t = vg >> 4, vkp = vg & 15;
    const float* src = Vg + ((size_t)bg * KVn + t * 32 + 2 * vkp) * Dn + d;
    const unsigned pr = pk2(src[0], src[Dn]);
    const int slot = (((d >> 3) ^ (d >> 1)) & 3) << 4;
    const size_t off = ((size_t)bg * NT32 + t) * 8192 + (d << 6)
                       + ((vkp * 4) ^ slot);
    *(unsigned*)(wsV + off) = pr;
  }
}

__global__ __launch_bounds__(512, 2)
void attn_fwd(const float* __restrict__ Qg, const float* __restrict__ Mg,
              const char* __restrict__ wsK, const char* __restrict__ wsV,
              float* __restrict__ Og) {
  __shared__ __align__(16) short Ks[2][KVB * Dn];    // 16KB x2
  __shared__ __align__(16) short Vt[2][Dn * KVB];    // 16KB x2
  __shared__ __align__(16) float Ms[2][QBLK * KVB];  // 8KB x2 (swizzled rows)

  const int tid = threadIdx.x;
  const int lane = tid & 63, w = tid >> 6;           // w in [0,8)
  const int hi = lane >> 5, ln = lane & 31;
  const int qb = blockIdx.x * QBLK, ho = blockIdx.y, b = blockIdx.z;
  const int h = ho * HO + w;                         // wave's head
  const int g = ho >> 1, bg = b * Gn + g;            // octet shares g

  // ---- Q B-fragments, PRE-SCALED: aq[ks][j] = Q[h][qb+ln][ks*16+hi*8+j]*SCALE2
  bf16x8 aq[8];
  {
    const float* qr = Qg + ((size_t)(b * Hn + h) * Qn + qb + ln) * Dn + hi * 8;
#pragma unroll
    for (int ks = 0; ks < 8; ++ks) {
      float4 f0 = *(const float4*)(qr + ks * 16);
      float4 f1 = *(const float4*)(qr + ks * 16 + 4);
      union { unsigned u[4]; bf16x8 b; } t;
      t.u[0] = pk2(f0.x * SCALE2, f0.y * SCALE2);
      t.u[1] = pk2(f0.z * SCALE2, f0.w * SCALE2);
      t.u[2] = pk2(f1.x * SCALE2, f1.y * SCALE2);
      t.u[3] = pk2(f1.z * SCALE2, f1.w * SCALE2);
      aq[ks] = t.b;
    }
  }

  // ---- incremental staging pointers (advance by constants; no per-tile mults)
  const char* wsKb = wsK + (size_t)bg * (KVn * 256);
  const char* wsVb = wsV + (size_t)bg * (KVn * 256);
  const int mr = w * 4 + (lane >> 4);
  const int mc = (lane & 15) << 4;
  const char* pM0 = (const char*)Mg + (size_t)(b * Qn + qb + mr) * (KVn * 4)
                    + (mc ^ ((mr & 15) << 4));
  const char* pK = wsKb + w * 2048 + lane * 16;      // K src, tile 0
  const char* pV = wsVb + w * 2048 + lane * 16;      // V src, tile 0
  const char* pM = pM0;                              // M src, tile 0
  char* dK0 = (char*)Ks[0] + w * 2048; char* dK1 = (char*)Ks[1] + w * 2048;
  char* dV0 = (char*)Vt[0] + w * 2048; char* dV1 = (char*)Vt[1] + w * 2048;
  char* dM0 = (char*)Ms[0] + w * 1024; char* dM1 = (char*)Ms[1] + w * 1024;

  auto gll = [](const char* s, char* d) {
    __builtin_amdgcn_global_load_lds(
        (const __attribute__((address_space(1))) void*)s,
        (__attribute__((address_space(3))) void*)d, 16, 0, 0);
  };
  auto stageK = [&](char* dk) { gll(pK, dk); gll(pK + 1024, dk + 1024); };
  auto stageVM = [&](char* dv, char* dm) {
    gll(pV, dv); gll(pV + 1024, dv + 1024); gll(pM, dm);
  };

  const int ksw = (ln & 15) << 4;
  const int msw = (ln & 15) << 4;
  const char* msb0 = (const char*)Ms[0] + ln * 256;
  const char* msb1 = (const char*)Ms[1] + ln * 256;

  auto qk = [&](const char* ksb, f32x16& t0, f32x16& t1) {
#pragma unroll
    for (int e = 0; e < 16; ++e) { t0[e] = 0.0f; t1[e] = 0.0f; }
    __builtin_amdgcn_s_setprio(1);
#pragma unroll
    for (int ks = 0; ks < 8; ++ks) {
      const int byte = (ks * 32 + hi * 16) ^ ksw;
      bf16x8 k0 = *(const bf16x8*)(ksb + (ln << 8) + byte);
      bf16x8 k1 = *(const bf16x8*)(ksb + ((32 + ln) << 8) + byte);
      t0 = __builtin_amdgcn_mfma_f32_32x32x16_bf16(k0, aq[ks], t0, 0, 0, 0);
      t1 = __builtin_amdgcn_mfma_f32_32x32x16_bf16(k1, aq[ks], t1, 0, 0, 0);
    }
    __builtin_amdgcn_s_setprio(0);
  };

  f32x16 o[4];
#pragma unroll
  for (int nt = 0; nt < 4; ++nt)
#pragma unroll
    for (int e = 0; e < 16; ++e) o[nt][e] = 0.0f;
  float lsum = 0.0f;

  // body(t): stage K(t+2)->Ks[cur], VM(t+1)->buf[nxt]; softmax(t) from sC;
  // QK(t+1)->sN from Ks[nxt]; PV(t); barrier. Pointers pre-advanced.
  auto body = [&](int t, f32x16& sC0, f32x16& sC1, f32x16& sN0, f32x16& sN1) {
    const int cur = t & 1;

    stageK(cur ? dK1 : dK0);
    stageVM(cur ? dV0 : dV1, cur ? dM0 : dM1);
    if (t + 3 < NT) pK += 16384;     // next body stages K(t+3)
    if (t + 2 < NT) { pV += 16384; pM += 256; }
    __builtin_amdgcn_sched_barrier(0);

    // ---- softmax(t): p = exp2(sC + mk*L2E)  [VALU chain first] ----
    const char* msb = cur ? msb1 : msb0;
    unsigned own0[8], own1[8];
    float psum = 0.0f;
#pragma unroll
    for (int gq = 0; gq < 4; ++gq) {
      float4 m0 = *(const float4*)(msb + ((gq * 32 + hi * 16) ^ msw));
      float4 m1 = *(const float4*)(msb + ((128 + gq * 32 + hi * 16) ^ msw));
      float p0 = __builtin_exp2f(__builtin_fmaf(m0.x, L2E, sC0[4 * gq + 0]));
      float p1 = __builtin_exp2f(__builtin_fmaf(m0.y, L2E, sC0[4 * gq + 1]));
      float p2 = __builtin_exp2f(__builtin_fmaf(m0.z, L2E, sC0[4 * gq + 2]));
      float p3 = __builtin_exp2f(__builtin_fmaf(m0.w, L2E, sC0[4 * gq + 3]));
      float q0 = __builtin_exp2f(__builtin_fmaf(m1.x, L2E, sC1[4 * gq + 0]));
      float q1 = __builtin_exp2f(__builtin_fmaf(m1.y, L2E, sC1[4 * gq + 1]));
      float q2 = __builtin_exp2f(__builtin_fmaf(m1.z, L2E, sC1[4 * gq + 2]));
      float q3 = __builtin_exp2f(__builtin_fmaf(m1.w, L2E, sC1[4 * gq + 3]));
      psum += ((p0 + p1) + (p2 + p3)) + ((q0 + q1) + (q2 + q3));
      own0[2 * gq] = pk2(p0, p1); own0[2 * gq + 1] = pk2(p2, p3);
      own1[2 * gq] = pk2(q0, q1); own1[2 * gq + 1] = pk2(q2, q3);
    }
    lsum += psum;

    // ---- QK(t+1) -> sN (independent; MFMAs fill softmax's VALU gaps) ----
    qk((const char*)Ks[cur ^ 1], sN0, sN1);

    // ---- P B-frags (permlane32_swap; verified) ----
    union Frag { unsigned u[4]; bf16x8 b; };
    Frag pf[4];
#pragma unroll
    for (int ks = 0; ks < 4; ++ks) {
      const unsigned* ow = (ks < 2) ? own0 : own1;
      const int bsl = (ks & 1) * 4;
#if __has_builtin(__builtin_amdgcn_permlane32_swap)
      u32x2 r0 = __builtin_amdgcn_permlane32_swap(ow[bsl + 0], ow[bsl + 2], false, false);
      u32x2 r1 = __builtin_amdgcn_permlane32_swap(ow[bsl + 1], ow[bsl + 3], false, false);
      pf[ks].u[0] = r0.x; pf[ks].u[2] = r0.y;
      pf[ks].u[1] = r1.x; pf[ks].u[3] = r1.y;
#else
      unsigned sA = __shfl_xor(ow[bsl + 0], 32), sCx = __shfl_xor(ow[bsl + 2], 32);
      unsigned sB = __shfl_xor(ow[bsl + 1], 32), sD = __shfl_xor(ow[bsl + 3], 32);
      pf[ks].u[0] = hi ? sCx : ow[bsl + 0];
      pf[ks].u[1] = hi ? sD : ow[bsl + 1];
      pf[ks].u[2] = hi ? ow[bsl + 2] : sA;
      pf[ks].u[3] = hi ? ow[bsl + 3] : sB;
#endif
    }

    // ---- PV(t): O^T[d][q] += V^T · P ----
    const char* vtb = (const char*)Vt[cur];
    __builtin_amdgcn_s_setprio(1);
#pragma unroll
    for (int nt = 0; nt < 4; ++nt) {
      const int d = nt * 32 + ln;
      const int swz = (((d >> 3) ^ (d >> 1)) & 3) << 4;
#pragma unroll
      for (int ks = 0; ks < 4; ++ks) {
        const int base = (ks >> 1) * 8192 + (d << 6);
        bf16x8 vfr = *(const bf16x8*)(vtb + base + (((ks & 1) * 32 + hi * 16) ^ swz));
        o[nt] = __builtin_amdgcn_mfma_f32_32x32x16_bf16(vfr, pf[ks].b, o[nt], 0, 0, 0);
      }
    }
    __builtin_amdgcn_s_setprio(0);

    __syncthreads();
  };

  // ---- prologue: K(0)->Ks[0], K(1)->Ks[1], V/M(0)->buf0; QK(0)->sA ----
  stageK(dK0); pK += 16384;         // staged K(0); pK -> K(1)
  stageK(dK1); pK += 16384;         // staged K(1); pK -> K(2)
  stageVM(dV0, dM0); pV += 16384; pM += 256;   // staged V/M(0); -> (1)
  __syncthreads();
  f32x16 sA0, sA1, sB0, sB1;
  qk((const char*)Ks[0], sA0, sA1);
  __syncthreads();   // all waves done reading Ks[0] before body(0) restages it

  for (int t = 0; t < NT; t += 2) {
    body(t, sA0, sA1, sB0, sB1);
    body(t + 1, sB0, sB1, sA0, sA1);
  }

  // ---- epilogue: O^T/l, write context[q][b][h*128+d] ----
  const float ltot = lsum + __shfl_xor(lsum, 32);
  const float invl = 1.0f / ltot;
  float* outp = Og + (size_t)(qb + ln) * (Bn * Hn * Dn) + (size_t)b * (Hn * Dn) + h * Dn;
#pragma unroll
  for (int nt = 0; nt < 4; ++nt)
#pragma unroll
    for (int gq = 0; gq < 4; ++gq) {
      float4 v;
      v.x = o[nt][gq * 4 + 0] * invl;
      v.y = o[nt][gq * 4 + 1] * invl;
      v.z = o[nt][gq * 4 + 2] * invl;
      v.w = o[nt][gq * 4 + 3] * invl;
      *(float4*)(outp + nt * 32 + gq * 8 + hi * 4) = v;
    }
}

extern "C" void kernel_launch(void* const* d_in, const int* in_sizes, int n_in,
                              void* d_out, int out_size, void* d_ws, size_t ws_size,
                              hipStream_t stream) {
  const float* q = (const float*)d_in[0];
  const float* k = (const float*)d_in[1];
  const float* v = (const float*)d_in[2];
  const float* m = (const float*)d_in[3];
  float* out = (float*)d_out;
  char* wsK = (char*)d_ws;
  char* wsV = wsK + WSK_BYTES;

  prepack<<<dim3((Bn * Gn * KVn * 64) / 256), 256, 0, stream>>>(k, v, wsK, wsV);
  dim3 grid(Qn / QBLK, Hn / HO, Bn);
  attn_fwd<<<grid, WAVES * 64, 0, stream>>>(q, m, wsK, wsV, out);
}